// Round 2
// baseline (555.250 us; speedup 1.0000x reference)
//
#include <hip/hip_runtime.h>
#include <hip/hip_bf16.h>

#define Nn 200000
#define Cc 1000
#define Dd 256

typedef float f32x4v __attribute__((ext_vector_type(4)));
typedef short bf16x8 __attribute__((ext_vector_type(8)));

__device__ __forceinline__ unsigned short f2bf(float x){
    union { float f; unsigned int u; } c; c.f = x;
    unsigned int u = c.u;
    u += 0x7fffu + ((u >> 16) & 1u);   // round-to-nearest-even
    return (unsigned short)(u >> 16);
}

// ---------------- weight prep: Wcat_t[col][k] bf16, col 0..255 = Wk, 256..511 = H1w ----------------
__global__ void k_prep_wcat(const float* __restrict__ Wk, const float* __restrict__ H1w,
                            unsigned short* __restrict__ wcat){
    int i = blockIdx.x * 256 + threadIdx.x;       // 512 blocks x 256
    int col = i >> 8, k = i & 255;
    float w = (col < Dd) ? Wk[k*Dd + col] : H1w[k*Dd + (col - Dd)];
    wcat[col*Dd + k] = f2bf(w);
}

// ---------------- per-cluster precompute, 4 clusters/block: qb = g@Wq + b_attn ;
//                  h_trans = tanh(g@Ws+bs) ; cterm = h_trans@G1w + G1b + H1b ----------------
__global__ __launch_bounds__(256)
void k_cluster_prep(const float* __restrict__ g, const float* __restrict__ Wq,
                    const float* __restrict__ b_attn,
                    const float* __restrict__ Ws, const float* __restrict__ bs,
                    const float* __restrict__ G1w, const float* __restrict__ G1b,
                    const float* __restrict__ H1b,
                    float* __restrict__ qb, float* __restrict__ h_trans,
                    float* __restrict__ cterm){
    int c0 = blockIdx.x * 4, d = threadIdx.x;
    __shared__ float gL[4][Dd], htL[4][Dd];
    #pragma unroll
    for (int j = 0; j < 4; ++j) gL[j][d] = g[(size_t)(c0+j)*Dd + d];
    __syncthreads();
    float ba = b_attn[d], bsv = bs[d];
    float aq[4], as[4];
    #pragma unroll
    for (int j = 0; j < 4; ++j){ aq[j] = ba; as[j] = bsv; }
    #pragma unroll 4
    for (int k = 0; k < Dd; ++k){
        float wq = Wq[k*Dd + d], ws = Ws[k*Dd + d];
        #pragma unroll
        for (int j = 0; j < 4; ++j){
            aq[j] = fmaf(gL[j][k], wq, aq[j]);
            as[j] = fmaf(gL[j][k], ws, as[j]);
        }
    }
    #pragma unroll
    for (int j = 0; j < 4; ++j){
        qb[(size_t)(c0+j)*Dd + d] = aq[j];
        float ht = tanhf(as[j]);
        h_trans[(size_t)(c0+j)*Dd + d] = ht;
        htL[j][d] = ht;
    }
    __syncthreads();
    float bc = H1b[d] + G1b[d];
    float ac[4];
    #pragma unroll
    for (int j = 0; j < 4; ++j) ac[j] = bc;
    #pragma unroll 4
    for (int k = 0; k < Dd; ++k){
        float gw = G1w[k*Dd + d];
        #pragma unroll
        for (int j = 0; j < 4; ++j) ac[j] = fmaf(htL[j][k], gw, ac[j]);
    }
    #pragma unroll
    for (int j = 0; j < 4; ++j) cterm[(size_t)(c0+j)*Dd + d] = ac[j];
}

// ---------------- counting sort of nodes by cluster ----------------
__global__ void k_zero(int* __restrict__ hist){
    int i = blockIdx.x*256 + threadIdx.x;
    if (i < Cc) hist[i] = 0;
}
__global__ void k_hist(const int* __restrict__ seg, int* __restrict__ hist){
    int i = blockIdx.x*256 + threadIdx.x;
    if (i < Nn) atomicAdd(&hist[seg[i]], 1);
}
__global__ void k_scan(const int* __restrict__ hist, int* __restrict__ offs, int* __restrict__ cursor){
    __shared__ int sc[1024];
    int t = threadIdx.x;
    int v = (t < Cc) ? hist[t] : 0;
    sc[t] = v;
    __syncthreads();
    for (int off = 1; off < 1024; off <<= 1){
        int add = (t >= off) ? sc[t - off] : 0;
        __syncthreads();
        sc[t] += add;
        __syncthreads();
    }
    if (t < Cc){
        int excl = sc[t] - v;
        offs[t] = excl;
        cursor[t] = excl;
    }
}
__global__ void k_scatter(const int* __restrict__ seg, int* __restrict__ cursor, int* __restrict__ order){
    int i = blockIdx.x*256 + threadIdx.x;
    if (i < Nn){
        int p = atomicAdd(&cursor[seg[i]], 1);
        order[p] = i;
    }
}

// ---------------- the big fused kernel: Y = h_bf16 @ [Wk|H1w]  (64 rows x 512 cols / block)
//                  epilogue via LDS re-stage: e = exp(s) and h_merged, all float4-coalesced ----------------
__global__ __launch_bounds__(512)
void k_gemm_fused(const float* __restrict__ h,
                  const unsigned short* __restrict__ wcat,
                  const int* __restrict__ seg,
                  const float* __restrict__ qb,
                  const float* __restrict__ w_score,
                  const float* __restrict__ b_score,
                  const float* __restrict__ cterm,
                  const float* __restrict__ h_trans,
                  float* __restrict__ e,
                  float* __restrict__ out){
    // smem: main loop -> bf16 A tile 64x256 XOR-swizzled (32 KiB)
    //       epilogue  -> fp32 stage kS[64][132] (33792 B)
    __shared__ __align__(16) char smem[64*132*4];
    __shared__ int segL[64];

    int tid = threadIdx.x;
    int w = tid >> 6, l = tid & 63;
    int rowBase = blockIdx.x * 64;

    // ---- stage A tile fp32 -> bf16 (coalesced float4 reads, swizzled 8B LDS writes) ----
    const float4* hv = reinterpret_cast<const float4*>(h + (size_t)rowBase * Dd);
    #pragma unroll
    for (int j = 0; j < 8; ++j){
        int f = j*512 + tid;              // float4 id in 64x256 tile
        int row = f >> 6;
        int k4  = (f & 63) << 2;
        float4 v = hv[f];
        unsigned long long pk = (unsigned long long)f2bf(v.x)
                              | ((unsigned long long)f2bf(v.y) << 16)
                              | ((unsigned long long)f2bf(v.z) << 32)
                              | ((unsigned long long)f2bf(v.w) << 48);
        int byte = (row*512 + k4*2) ^ ((row & 7) << 4);
        *reinterpret_cast<unsigned long long*>(smem + byte) = pk;
    }
    if (tid < 64) segL[tid] = seg[rowBase + tid];
    __syncthreads();

    int grp = l >> 4, rlo = l & 15;
    int wcol = w * 64;

    f32x4v acc[4][4];
    #pragma unroll
    for (int mt = 0; mt < 4; ++mt)
        #pragma unroll
        for (int nt = 0; nt < 4; ++nt)
            acc[mt][nt] = (f32x4v){0.f, 0.f, 0.f, 0.f};

    // ---- main loop, double-buffered A(ds) + B(global L2) fragments ----
    const char* bP[4];
    #pragma unroll
    for (int nt = 0; nt < 4; ++nt)
        bP[nt] = reinterpret_cast<const char*>(wcat + (size_t)(wcol + nt*16 + rlo)*Dd + grp*8);

    bf16x8 aC[4], aN[4], bC[4], bN[4];
    #pragma unroll
    for (int nt = 0; nt < 4; ++nt) bC[nt] = *reinterpret_cast<const bf16x8*>(bP[nt]);
    #pragma unroll
    for (int mt = 0; mt < 4; ++mt){
        int row = mt*16 + rlo;
        int byte = (row*512 + grp*16) ^ ((row & 7) << 4);
        aC[mt] = *reinterpret_cast<const bf16x8*>(smem + byte);
    }

    #pragma unroll
    for (int kk = 0; kk < 8; ++kk){
        if (kk < 7){
            #pragma unroll
            for (int nt = 0; nt < 4; ++nt)
                bN[nt] = *reinterpret_cast<const bf16x8*>(bP[nt] + (kk+1)*64);
            #pragma unroll
            for (int mt = 0; mt < 4; ++mt){
                int row = mt*16 + rlo;
                int byte = (row*512 + (kk+1)*64 + grp*16) ^ ((row & 7) << 4);
                aN[mt] = *reinterpret_cast<const bf16x8*>(smem + byte);
            }
        }
        #pragma unroll
        for (int mt = 0; mt < 4; ++mt)
            #pragma unroll
            for (int nt = 0; nt < 4; ++nt)
                acc[mt][nt] = __builtin_amdgcn_mfma_f32_16x16x32_bf16(aC[mt], bC[nt], acc[mt][nt], 0, 0, 0);
        if (kk < 7){
            #pragma unroll
            for (int x = 0; x < 4; ++x){ aC[x] = aN[x]; bC[x] = bN[x]; }
        }
    }
    __syncthreads();   // A tile dead; smem becomes fp32 stage

    // ---- epilogue: 4 phases of 64 rows x 128 cols through LDS ----
    float (*kS)[132] = reinterpret_cast<float(*)[132]>(smem);
    int row_t = tid >> 3;            // 0..63
    int c8    = (tid & 7) * 16;      // 0..112
    int sgt   = segL[row_t];
    float sp  = 0.f;

    #pragma unroll
    for (int p = 0; p < 4; ++p){
        if ((w >> 1) == p){
            int cb = (w & 1) * 64;
            #pragma unroll
            for (int mt = 0; mt < 4; ++mt)
                #pragma unroll
                for (int nt = 0; nt < 4; ++nt){
                    int cc = cb + nt*16 + rlo;
                    int rr = mt*16 + grp*4;
                    #pragma unroll
                    for (int i = 0; i < 4; ++i) kS[rr + i][cc] = acc[mt][nt][i];
                }
        }
        __syncthreads();
        if (p < 2){
            // score cols p*128 + c8 .. +15 : sp += tanh(k + qb[seg])*w_score
            int gc = p*128 + c8;
            const float* qrow = qb + (size_t)sgt*Dd + gc;
            const float* wsr  = w_score + gc;
            #pragma unroll
            for (int j = 0; j < 4; ++j){
                float4 kv = *reinterpret_cast<float4*>(&kS[row_t][c8 + 4*j]);
                float4 q4 = *reinterpret_cast<const float4*>(qrow + 4*j);
                float4 w4 = *reinterpret_cast<const float4*>(wsr + 4*j);
                sp = fmaf(tanhf(kv.x + q4.x), w4.x, sp);
                sp = fmaf(tanhf(kv.y + q4.y), w4.y, sp);
                sp = fmaf(tanhf(kv.z + q4.z), w4.z, sp);
                sp = fmaf(tanhf(kv.w + q4.w), w4.w, sp);
            }
            if (p == 1){
                sp += __shfl_xor(sp, 1);
                sp += __shfl_xor(sp, 2);
                sp += __shfl_xor(sp, 4);
                if ((tid & 7) == 0)
                    e[rowBase + row_t] = expf(sp + b_score[0]);  // unshifted: |s| small, ratio == ref
            }
        } else {
            // merge cols (p-2)*128 + c8 : z1 = sigmoid(y + cterm[seg]); gated merge, float4 out
            int gc = (p - 2)*128 + c8;
            const float* ct = cterm   + (size_t)sgt*Dd + gc;
            const float* ht = h_trans + (size_t)sgt*Dd + gc;
            const float* hr = h   + (size_t)(rowBase + row_t)*Dd + gc;
            float*       po = out + (size_t)(rowBase + row_t)*Dd + gc;
            #pragma unroll
            for (int j = 0; j < 4; ++j){
                float4 yv = *reinterpret_cast<float4*>(&kS[row_t][c8 + 4*j]);
                float4 c4 = *reinterpret_cast<const float4*>(ct + 4*j);
                float4 t4 = *reinterpret_cast<const float4*>(ht + 4*j);
                float4 h4 = *reinterpret_cast<const float4*>(hr + 4*j);
                float4 o4;
                float z;
                z = 1.f / (1.f + expf(-(yv.x + c4.x))); o4.x = (1.f - z)*h4.x + z*t4.x;
                z = 1.f / (1.f + expf(-(yv.y + c4.y))); o4.y = (1.f - z)*h4.y + z*t4.y;
                z = 1.f / (1.f + expf(-(yv.z + c4.z))); o4.z = (1.f - z)*h4.z + z*t4.z;
                z = 1.f / (1.f + expf(-(yv.w + c4.w))); o4.w = (1.f - z)*h4.w + z*t4.w;
                *reinterpret_cast<float4*>(po + 4*j) = o4;
            }
        }
        if (p < 3) __syncthreads();
    }
}

// ---------------- per-cluster ctx = sum(e*h)/sum(e) over sorted node lists ----------------
__global__ __launch_bounds__(256)
void k_ctx(const float* __restrict__ h, const float* __restrict__ e,
           const int* __restrict__ order, const int* __restrict__ hist,
           const int* __restrict__ offs, float* __restrict__ ctx){
    int c = blockIdx.x, d = threadIdx.x;
    __shared__ int idxL[1024];
    __shared__ float eL[1024];
    __shared__ float red[256];
    int cnt = hist[c], start = offs[c];
    const float* hd = h + d;
    float a0 = 0.f, a1 = 0.f, a2 = 0.f, a3 = 0.f, dpart = 0.f;
    for (int base = 0; base < cnt; base += 1024){
        int m = min(1024, cnt - base);
        for (int i = d; i < m; i += 256){
            int n = order[start + base + i];
            idxL[i] = n;
            float ev = e[n];
            eL[i] = ev;
            dpart += ev;
        }
        __syncthreads();
        int i = 0;
        for (; i + 4 <= m; i += 4){
            a0 = fmaf(eL[i  ], hd[(size_t)idxL[i  ]*Dd], a0);
            a1 = fmaf(eL[i+1], hd[(size_t)idxL[i+1]*Dd], a1);
            a2 = fmaf(eL[i+2], hd[(size_t)idxL[i+2]*Dd], a2);
            a3 = fmaf(eL[i+3], hd[(size_t)idxL[i+3]*Dd], a3);
        }
        for (; i < m; ++i)
            a0 = fmaf(eL[i], hd[(size_t)idxL[i]*Dd], a0);
        __syncthreads();
    }
    red[d] = dpart;
    for (int s_ = 128; s_ > 0; s_ >>= 1){
        __syncthreads();
        if (d < s_) red[d] += red[d + s_];
    }
    __syncthreads();
    float denom = red[0];
    float inv = (denom > 0.f) ? 1.f/denom : 0.f;   // empty cluster -> ctx = 0 (matches ref)
    ctx[c*Dd + d] = ((a0 + a1) + (a2 + a3)) * inv;
}

// ---------------- virtual-node side, 4 clusters/block: g_trans = tanh(ctx@Wv+bv); z2 gate ----------------
__global__ __launch_bounds__(256)
void k_vn(const float* __restrict__ ctx, const float* __restrict__ g_hat,
          const float* __restrict__ Wv, const float* __restrict__ bv,
          const float* __restrict__ H2w, const float* __restrict__ H2b,
          const float* __restrict__ G2w, const float* __restrict__ G2b,
          float* __restrict__ out){
    int c0 = blockIdx.x * 4, d = threadIdx.x;
    __shared__ float cL[4][Dd], gtL[4][Dd], ghL[4][Dd];
    #pragma unroll
    for (int j = 0; j < 4; ++j){
        cL[j][d]  = ctx[(size_t)(c0+j)*Dd + d];
        ghL[j][d] = g_hat[(size_t)(c0+j)*Dd + d];
    }
    __syncthreads();
    float bvv = bv[d];
    float a1[4];
    #pragma unroll
    for (int j = 0; j < 4; ++j) a1[j] = bvv;
    #pragma unroll 4
    for (int k = 0; k < Dd; ++k){
        float wv = Wv[k*Dd + d];
        #pragma unroll
        for (int j = 0; j < 4; ++j) a1[j] = fmaf(cL[j][k], wv, a1[j]);
    }
    #pragma unroll
    for (int j = 0; j < 4; ++j) gtL[j][d] = tanhf(a1[j]);
    __syncthreads();
    float b2 = H2b[d] + G2b[d];
    float a2[4];
    #pragma unroll
    for (int j = 0; j < 4; ++j) a2[j] = b2;
    #pragma unroll 4
    for (int k = 0; k < Dd; ++k){
        float hw = H2w[k*Dd + d], gw = G2w[k*Dd + d];
        #pragma unroll
        for (int j = 0; j < 4; ++j){
            a2[j] = fmaf(gtL[j][k], hw, a2[j]);
            a2[j] = fmaf(ghL[j][k], gw, a2[j]);
        }
    }
    #pragma unroll
    for (int j = 0; j < 4; ++j){
        float z = 1.f / (1.f + expf(-a2[j]));
        float gt = gtL[j][d];
        out[(size_t)(Nn + c0 + j)*Dd + d] = (1.f - z)*gt + z*ghL[j][d];
    }
}

extern "C" void kernel_launch(void* const* d_in, const int* in_sizes, int n_in,
                              void* d_out, int out_size, void* d_ws, size_t ws_size,
                              hipStream_t stream){
    const float* h       = (const float*)d_in[0];
    const float* g       = (const float*)d_in[1];
    const float* g_hat   = (const float*)d_in[2];
    const int*   seg     = (const int*)  d_in[3];
    const float* Wq      = (const float*)d_in[4];
    const float* Wk      = (const float*)d_in[5];
    const float* b_attn  = (const float*)d_in[6];
    const float* w_score = (const float*)d_in[7];
    const float* b_score = (const float*)d_in[8];
    const float* Wv      = (const float*)d_in[9];
    const float* bv      = (const float*)d_in[10];
    const float* Ws      = (const float*)d_in[11];
    const float* bs      = (const float*)d_in[12];
    const float* H1w     = (const float*)d_in[13];
    const float* H1b     = (const float*)d_in[14];
    const float* G1w     = (const float*)d_in[15];
    const float* G1b     = (const float*)d_in[16];
    const float* H2w     = (const float*)d_in[17];
    const float* H2b     = (const float*)d_in[18];
    const float* G2w     = (const float*)d_in[19];
    const float* G2b     = (const float*)d_in[20];
    float* out = (float*)d_out;

    char* ws = (char*)d_ws;
    unsigned short* wcat = (unsigned short*)(ws + 0);        // 262144 B
    float* qb      = (float*)(ws + 262144);                  // 1,024,000 B
    float* h_trans = (float*)(ws + 1286144);                 // 1,024,000 B
    float* cterm   = (float*)(ws + 2310144);                 // 1,024,000 B
    float* ctx     = (float*)(ws + 3334144);                 // 1,024,000 B
    float* e       = (float*)(ws + 4358144);                 //   800,000 B
    int*   order   = (int*)  (ws + 5158144);                 //   800,000 B
    int*   hist    = (int*)  (ws + 5958144);                 //     4,000 B
    int*   offs    = (int*)  (ws + 5962240);                 //     4,000 B
    int*   cursor  = (int*)  (ws + 5966336);                 //     4,000 B

    hipLaunchKernelGGL(k_prep_wcat, dim3(512), dim3(256), 0, stream, Wk, H1w, wcat);
    hipLaunchKernelGGL(k_cluster_prep, dim3(Cc/4), dim3(256), 0, stream,
                       g, Wq, b_attn, Ws, bs, G1w, G1b, H1b, qb, h_trans, cterm);
    hipLaunchKernelGGL(k_zero, dim3(4), dim3(256), 0, stream, hist);
    hipLaunchKernelGGL(k_hist, dim3((Nn + 255)/256), dim3(256), 0, stream, seg, hist);
    hipLaunchKernelGGL(k_scan, dim3(1), dim3(1024), 0, stream, hist, offs, cursor);
    hipLaunchKernelGGL(k_scatter, dim3((Nn + 255)/256), dim3(256), 0, stream, seg, cursor, order);
    hipLaunchKernelGGL(k_gemm_fused, dim3(Nn/64), dim3(512), 0, stream,
                       h, wcat, seg, qb, w_score, b_score, cterm, h_trans, e, out);
    hipLaunchKernelGGL(k_ctx, dim3(Cc), dim3(256), 0, stream, h, e, order, hist, offs, ctx);
    hipLaunchKernelGGL(k_vn, dim3(Cc/4), dim3(256), 0, stream,
                       ctx, g_hat, Wv, bv, H2w, H2b, G2w, G2b, out);
}

// Round 3
// 536.206 us; speedup vs baseline: 1.0355x; 1.0355x over previous
//
#include <hip/hip_runtime.h>
#include <hip/hip_bf16.h>

#define Nn 200000
#define Cc 1000
#define Dd 256

typedef float f32x4v __attribute__((ext_vector_type(4)));
typedef short bf16x8 __attribute__((ext_vector_type(8)));

__device__ __forceinline__ unsigned short f2bf(float x){
    union { float f; unsigned int u; } c; c.f = x;
    unsigned int u = c.u;
    u += 0x7fffu + ((u >> 16) & 1u);   // round-to-nearest-even
    return (unsigned short)(u >> 16);
}

// ---------------- weight prep: Wcat_t[col][k] bf16, col 0..255 = Wk, 256..511 = H1w ----------------
__global__ void k_prep_wcat(const float* __restrict__ Wk, const float* __restrict__ H1w,
                            unsigned short* __restrict__ wcat){
    int i = blockIdx.x * 256 + threadIdx.x;       // 512 blocks x 256
    int col = i >> 8, k = i & 255;
    float w = (col < Dd) ? Wk[k*Dd + col] : H1w[k*Dd + (col - Dd)];
    wcat[col*Dd + k] = f2bf(w);
}

// ---------------- per-cluster precompute (1 cluster/block, 1000 blocks): qb = g@Wq + b_attn ;
//                  h_trans = tanh(g@Ws+bs) ; cterm = h_trans@G1w + G1b + H1b ----------------
__global__ __launch_bounds__(256)
void k_cluster_prep(const float* __restrict__ g, const float* __restrict__ Wq,
                    const float* __restrict__ b_attn,
                    const float* __restrict__ Ws, const float* __restrict__ bs,
                    const float* __restrict__ G1w, const float* __restrict__ G1b,
                    const float* __restrict__ H1b,
                    float* __restrict__ qb, float* __restrict__ h_trans,
                    float* __restrict__ cterm){
    int c = blockIdx.x, d = threadIdx.x;
    __shared__ float gL[Dd], htL[Dd];
    gL[d] = g[(size_t)c*Dd + d];
    __syncthreads();
    float aq = b_attn[d], as = bs[d];
    #pragma unroll 4
    for (int k = 0; k < Dd; ++k){
        float gv = gL[k];
        aq = fmaf(gv, Wq[k*Dd + d], aq);
        as = fmaf(gv, Ws[k*Dd + d], as);
    }
    qb[(size_t)c*Dd + d] = aq;
    float ht = tanhf(as);
    h_trans[(size_t)c*Dd + d] = ht;
    htL[d] = ht;
    __syncthreads();
    float ac = H1b[d] + G1b[d];
    #pragma unroll 4
    for (int k = 0; k < Dd; ++k) ac = fmaf(htL[k], G1w[k*Dd + d], ac);
    cterm[(size_t)c*Dd + d] = ac;
}

// ---------------- counting sort of nodes by cluster ----------------
__global__ void k_zero(int* __restrict__ hist){
    int i = blockIdx.x*256 + threadIdx.x;
    if (i < Cc) hist[i] = 0;
}
__global__ void k_hist(const int* __restrict__ seg, int* __restrict__ hist){
    int i = blockIdx.x*256 + threadIdx.x;
    if (i < Nn) atomicAdd(&hist[seg[i]], 1);
}
__global__ void k_scan(const int* __restrict__ hist, int* __restrict__ offs, int* __restrict__ cursor){
    __shared__ int sc[1024];
    int t = threadIdx.x;
    int v = (t < Cc) ? hist[t] : 0;
    sc[t] = v;
    __syncthreads();
    for (int off = 1; off < 1024; off <<= 1){
        int add = (t >= off) ? sc[t - off] : 0;
        __syncthreads();
        sc[t] += add;
        __syncthreads();
    }
    if (t < Cc){
        int excl = sc[t] - v;
        offs[t] = excl;
        cursor[t] = excl;
    }
}
__global__ void k_scatter(const int* __restrict__ seg, int* __restrict__ cursor, int* __restrict__ order){
    int i = blockIdx.x*256 + threadIdx.x;
    if (i < Nn){
        int p = atomicAdd(&cursor[seg[i]], 1);
        order[p] = i;
    }
}

// ---------------- big fused kernel: Y = h_bf16 @ [Wk|H1w], 64 rows x 512 cols / block,
//                  4 sequential N-passes of 128 cols (16 acc regs) -> 2 blocks/CU ----------------
__global__ __launch_bounds__(512, 4)
void k_gemm_fused(const float* __restrict__ h,
                  const unsigned short* __restrict__ wcat,
                  const int* __restrict__ seg,
                  const float* __restrict__ qb,
                  const float* __restrict__ w_score,
                  const float* __restrict__ b_score,
                  const float* __restrict__ cterm,
                  const float* __restrict__ h_trans,
                  float* __restrict__ e,
                  float* __restrict__ out){
    __shared__ __align__(16) char aT[64*512];      // 32 KiB bf16 A tile, XOR-swizzled
    __shared__ __align__(16) float yS[64][132];    // 33.8 KiB fp32 per-pass Y stage
    __shared__ int segL[64];

    int tid = threadIdx.x;
    int w = tid >> 6, l = tid & 63;
    int rowBase = blockIdx.x * 64;

    // ---- stage A tile: batch all 8 float4 loads, then convert+write ----
    const float4* hv = reinterpret_cast<const float4*>(h + (size_t)rowBase * Dd);
    float4 v[8];
    #pragma unroll
    for (int j = 0; j < 8; ++j) v[j] = hv[j*512 + tid];
    if (tid < 64) segL[tid] = seg[rowBase + tid];
    #pragma unroll
    for (int j = 0; j < 8; ++j){
        int f = j*512 + tid;
        int row = f >> 6;
        unsigned long long pk = (unsigned long long)f2bf(v[j].x)
                              | ((unsigned long long)f2bf(v[j].y) << 16)
                              | ((unsigned long long)f2bf(v[j].z) << 32)
                              | ((unsigned long long)f2bf(v[j].w) << 48);
        int byte = (row*512 + (f & 63)*8) ^ ((row & 7) << 4);
        *reinterpret_cast<unsigned long long*>(aT + byte) = pk;
    }
    __syncthreads();

    int grp = l >> 4, rlo = l & 15;
    int row_t = tid >> 3;            // 0..63 (epilogue row)
    int c8    = (tid & 7) * 16;      // 0..112 (epilogue col base within 128)
    int sgt   = segL[row_t];
    float sp  = 0.f;                 // score partial across passes 0..1

    for (int pass = 0; pass < 4; ++pass){
        // ---- main loop for this 128-col pass: per wave 16 cols, acc 4x1 frags ----
        int colw = pass*128 + w*16 + rlo;
        const char* bPt = reinterpret_cast<const char*>(wcat + (size_t)colw*Dd) + grp*16;
        f32x4v acc[4];
        #pragma unroll
        for (int mt = 0; mt < 4; ++mt) acc[mt] = (f32x4v){0.f,0.f,0.f,0.f};

        bf16x8 bC = *reinterpret_cast<const bf16x8*>(bPt), bN;
        bf16x8 aC[4], aN[4];
        #pragma unroll
        for (int mt = 0; mt < 4; ++mt){
            int row = mt*16 + rlo;
            int byte = (row*512 + grp*16) ^ ((row & 7) << 4);
            aC[mt] = *reinterpret_cast<const bf16x8*>(aT + byte);
        }
        #pragma unroll
        for (int kk = 0; kk < 8; ++kk){
            if (kk < 7){
                bN = *reinterpret_cast<const bf16x8*>(bPt + (kk+1)*64);
                #pragma unroll
                for (int mt = 0; mt < 4; ++mt){
                    int row = mt*16 + rlo;
                    int byte = (row*512 + (kk+1)*64 + grp*16) ^ ((row & 7) << 4);
                    aN[mt] = *reinterpret_cast<const bf16x8*>(aT + byte);
                }
            }
            #pragma unroll
            for (int mt = 0; mt < 4; ++mt)
                acc[mt] = __builtin_amdgcn_mfma_f32_16x16x32_bf16(aC[mt], bC, acc[mt], 0, 0, 0);
            if (kk < 7){
                #pragma unroll
                for (int mt = 0; mt < 4; ++mt) aC[mt] = aN[mt];
                bC = bN;
            }
        }

        __syncthreads();   // previous pass finished reading yS
        // ---- dump this pass's 64x128 Y into LDS ----
        #pragma unroll
        for (int mt = 0; mt < 4; ++mt)
            #pragma unroll
            for (int i = 0; i < 4; ++i)
                yS[mt*16 + grp*4 + i][w*16 + rlo] = acc[mt][i];
        __syncthreads();

        if (pass < 2){
            // score cols pass*128 + c8 .. +15 : sp += tanh(k + qb[seg])*w_score
            int gc = pass*128 + c8;
            const float* qrow = qb + (size_t)sgt*Dd + gc;
            const float* wsr  = w_score + gc;
            #pragma unroll
            for (int j = 0; j < 4; ++j){
                float4 kv = *reinterpret_cast<float4*>(&yS[row_t][c8 + 4*j]);
                float4 q4 = *reinterpret_cast<const float4*>(qrow + 4*j);
                float4 w4 = *reinterpret_cast<const float4*>(wsr + 4*j);
                sp = fmaf(tanhf(kv.x + q4.x), w4.x, sp);
                sp = fmaf(tanhf(kv.y + q4.y), w4.y, sp);
                sp = fmaf(tanhf(kv.z + q4.z), w4.z, sp);
                sp = fmaf(tanhf(kv.w + q4.w), w4.w, sp);
            }
            if (pass == 1){
                sp += __shfl_xor(sp, 1);
                sp += __shfl_xor(sp, 2);
                sp += __shfl_xor(sp, 4);
                if ((tid & 7) == 0)
                    e[rowBase + row_t] = expf(sp + b_score[0]);  // unshifted: |s| small, ratio == ref
            }
        } else {
            // merge cols (pass-2)*128 + c8 : z1 = sigmoid(y + cterm[seg]); gated merge, float4 out
            int gc = (pass - 2)*128 + c8;
            const float* ct = cterm   + (size_t)sgt*Dd + gc;
            const float* ht = h_trans + (size_t)sgt*Dd + gc;
            const float* hr = h   + (size_t)(rowBase + row_t)*Dd + gc;
            float*       po = out + (size_t)(rowBase + row_t)*Dd + gc;
            #pragma unroll
            for (int j = 0; j < 4; ++j){
                float4 yv = *reinterpret_cast<float4*>(&yS[row_t][c8 + 4*j]);
                float4 c4 = *reinterpret_cast<const float4*>(ct + 4*j);
                float4 t4 = *reinterpret_cast<const float4*>(ht + 4*j);
                float4 h4 = *reinterpret_cast<const float4*>(hr + 4*j);
                float4 o4;
                float z;
                z = 1.f / (1.f + expf(-(yv.x + c4.x))); o4.x = (1.f - z)*h4.x + z*t4.x;
                z = 1.f / (1.f + expf(-(yv.y + c4.y))); o4.y = (1.f - z)*h4.y + z*t4.y;
                z = 1.f / (1.f + expf(-(yv.z + c4.z))); o4.z = (1.f - z)*h4.z + z*t4.z;
                z = 1.f / (1.f + expf(-(yv.w + c4.w))); o4.w = (1.f - z)*h4.w + z*t4.w;
                *reinterpret_cast<float4*>(po + 4*j) = o4;
            }
        }
    }
}

// ---------------- per-cluster ctx partials: 4 chunk-blocks per cluster, no atomics ----------------
__global__ __launch_bounds__(256)
void k_ctx(const float* __restrict__ h, const float* __restrict__ e,
           const int* __restrict__ order, const int* __restrict__ hist,
           const int* __restrict__ offs,
           float* __restrict__ ctxPart, float* __restrict__ denPart){
    int b = blockIdx.x;              // 0..3999
    int c = b >> 2, q = b & 3;
    int cnt = hist[c], start0 = offs[c];
    int c0 = (cnt * q) >> 2, c1 = (cnt * (q+1)) >> 2;
    int n = c1 - c0;
    int start = start0 + c0;
    int t = threadIdx.x;
    __shared__ int idxL[512];
    __shared__ float eL[512];
    __shared__ float redL[4][256];
    __shared__ float dsum[4];
    int r4 = t >> 6;                 // wave id: rows == r4 mod 4
    int col4 = (t & 63) << 2;        // float4 column
    f32x4v acc = {0.f,0.f,0.f,0.f};
    float dpart = 0.f;
    for (int base = 0; base < n; base += 512){
        int m = min(512, n - base);
        for (int i = t; i < m; i += 256){
            int nd = order[start + base + i];
            idxL[i] = nd;
            float ev = e[nd];
            eL[i] = ev;
            dpart += ev;
        }
        __syncthreads();
        for (int i = r4; i < m; i += 4){
            float ev = eL[i];
            float4 hv = *reinterpret_cast<const float4*>(h + (size_t)idxL[i]*Dd + col4);
            acc.x = fmaf(ev, hv.x, acc.x);
            acc.y = fmaf(ev, hv.y, acc.y);
            acc.z = fmaf(ev, hv.z, acc.z);
            acc.w = fmaf(ev, hv.w, acc.w);
        }
        __syncthreads();
    }
    *reinterpret_cast<float4*>(&redL[r4][col4]) = (float4){acc.x, acc.y, acc.z, acc.w};
    #pragma unroll
    for (int off = 1; off < 64; off <<= 1) dpart += __shfl_xor(dpart, off);
    if ((t & 63) == 0) dsum[r4] = dpart;
    __syncthreads();
    if (t < 256){
        float s = redL[0][t] + redL[1][t] + redL[2][t] + redL[3][t];
        ctxPart[((size_t)c*4 + q)*Dd + t] = s;
    }
    if (t == 0) denPart[b] = dsum[0] + dsum[1] + dsum[2] + dsum[3];
}

// ---------------- virtual-node side (1 cluster/block): combine ctx partials, then
//                  g_trans = tanh(ctx@Wv+bv); z2 gate; out rows N..N+C-1 ----------------
__global__ __launch_bounds__(256)
void k_vn(const float* __restrict__ ctxPart, const float* __restrict__ denPart,
          const float* __restrict__ g_hat,
          const float* __restrict__ Wv, const float* __restrict__ bv,
          const float* __restrict__ H2w, const float* __restrict__ H2b,
          const float* __restrict__ G2w, const float* __restrict__ G2b,
          float* __restrict__ out){
    int c = blockIdx.x, d = threadIdx.x;
    __shared__ float cL[Dd], gtL[Dd], ghL[Dd];
    float den = denPart[c*4] + denPart[c*4+1] + denPart[c*4+2] + denPart[c*4+3];
    float inv = (den > 0.f) ? 1.f/den : 0.f;   // empty cluster -> ctx = 0 (matches ref)
    float num = ctxPart[((size_t)c*4 + 0)*Dd + d] + ctxPart[((size_t)c*4 + 1)*Dd + d]
              + ctxPart[((size_t)c*4 + 2)*Dd + d] + ctxPart[((size_t)c*4 + 3)*Dd + d];
    cL[d]  = num * inv;
    ghL[d] = g_hat[(size_t)c*Dd + d];
    __syncthreads();
    float a1 = bv[d];
    #pragma unroll 4
    for (int k = 0; k < Dd; ++k) a1 = fmaf(cL[k], Wv[k*Dd + d], a1);
    float gt = tanhf(a1);
    gtL[d] = gt;
    __syncthreads();
    float a2 = H2b[d] + G2b[d];
    #pragma unroll 4
    for (int k = 0; k < Dd; ++k){
        a2 = fmaf(gtL[k], H2w[k*Dd + d], a2);
        a2 = fmaf(ghL[k], G2w[k*Dd + d], a2);
    }
    float z = 1.f / (1.f + expf(-a2));
    out[(size_t)(Nn + c)*Dd + d] = (1.f - z)*gt + z*ghL[d];
}

extern "C" void kernel_launch(void* const* d_in, const int* in_sizes, int n_in,
                              void* d_out, int out_size, void* d_ws, size_t ws_size,
                              hipStream_t stream){
    const float* h       = (const float*)d_in[0];
    const float* g       = (const float*)d_in[1];
    const float* g_hat   = (const float*)d_in[2];
    const int*   seg     = (const int*)  d_in[3];
    const float* Wq      = (const float*)d_in[4];
    const float* Wk      = (const float*)d_in[5];
    const float* b_attn  = (const float*)d_in[6];
    const float* w_score = (const float*)d_in[7];
    const float* b_score = (const float*)d_in[8];
    const float* Wv      = (const float*)d_in[9];
    const float* bv      = (const float*)d_in[10];
    const float* Ws      = (const float*)d_in[11];
    const float* bs      = (const float*)d_in[12];
    const float* H1w     = (const float*)d_in[13];
    const float* H1b     = (const float*)d_in[14];
    const float* G1w     = (const float*)d_in[15];
    const float* G1b     = (const float*)d_in[16];
    const float* H2w     = (const float*)d_in[17];
    const float* H2b     = (const float*)d_in[18];
    const float* G2w     = (const float*)d_in[19];
    const float* G2b     = (const float*)d_in[20];
    float* out = (float*)d_out;

    char* ws = (char*)d_ws;
    unsigned short* wcat = (unsigned short*)(ws + 0);        //   262,144 B
    float* qb      = (float*)(ws +  262144);                 // 1,024,000 B
    float* h_trans = (float*)(ws + 1286144);                 // 1,024,000 B
    float* cterm   = (float*)(ws + 2310144);                 // 1,024,000 B
    float* e       = (float*)(ws + 3334144);                 //   800,000 B
    int*   order   = (int*)  (ws + 4134144);                 //   800,000 B
    int*   hist    = (int*)  (ws + 4934144);                 //     4,000 B
    int*   offs    = (int*)  (ws + 4938144);                 //     4,000 B
    int*   cursor  = (int*)  (ws + 4942144);                 //     4,000 B
    float* ctxPart = (float*)(ws + 4946144);                 // 4,096,000 B
    float* denPart = (float*)(ws + 9042144);                 //    16,000 B

    hipLaunchKernelGGL(k_prep_wcat, dim3(512), dim3(256), 0, stream, Wk, H1w, wcat);
    hipLaunchKernelGGL(k_cluster_prep, dim3(Cc), dim3(256), 0, stream,
                       g, Wq, b_attn, Ws, bs, G1w, G1b, H1b, qb, h_trans, cterm);
    hipLaunchKernelGGL(k_zero, dim3(4), dim3(256), 0, stream, hist);
    hipLaunchKernelGGL(k_hist, dim3((Nn + 255)/256), dim3(256), 0, stream, seg, hist);
    hipLaunchKernelGGL(k_scan, dim3(1), dim3(1024), 0, stream, hist, offs, cursor);
    hipLaunchKernelGGL(k_scatter, dim3((Nn + 255)/256), dim3(256), 0, stream, seg, cursor, order);
    hipLaunchKernelGGL(k_gemm_fused, dim3(Nn/64), dim3(512), 0, stream,
                       h, wcat, seg, qb, w_score, b_score, cterm, h_trans, e, out);
    hipLaunchKernelGGL(k_ctx, dim3(Cc*4), dim3(256), 0, stream, h, e, order, hist, offs, ctxPart, denPart);
    hipLaunchKernelGGL(k_vn, dim3(Cc), dim3(256), 0, stream,
                       ctxPart, denPart, g_hat, Wv, bv, H2w, H2b, G2w, G2b, out);
}